// Round 19
// baseline (418.862 us; speedup 1.0000x reference)
//
#include <hip/hip_runtime.h>
#include <hip/hip_bf16.h>
#include <cstdint>
#include <cstddef>

#define TEXT_H_   4096
#define S_TOK     4096
#define P_TOK     1024
#define ROWS_PB   3072            // rows per batch after dropping s<1024
#define M_ROWS    6144            // 2 * 3072
#define NK        4096            // N and K of both GEMMs
#define BK        64
#define NT        (NK / BK)       // 64 K-tiles

// compacted GEMM: 224x256 tile (7 row-blocks/wave-half), 8 waves, r14 engine
#define BM0       224
#define BN        256
#define NWGC      448             // worst-case 28 M-tiles x 16 N-tiles
#define TW2_BLKS  32              // dual-panel W2-transpose blocks inside GEMM1
#define SLOT0_BYTES (64 * 1024)   // A chunks 0-31 (256 rows staged; 224 used), B 32-63
#define LDS0_TOTAL  (2 * SLOT0_BYTES)

typedef __attribute__((ext_vector_type(8))) short  bf16x8_t;
typedef __attribute__((ext_vector_type(4))) float  f32x4_t;
typedef __attribute__((ext_vector_type(4))) float  fl4_t;
typedef __attribute__((ext_vector_type(4))) ushort u16x4_t;
typedef __attribute__((ext_vector_type(8))) ushort u16x8_t;

__device__ int g_meff;            // number of masked (active) rows
__device__ int g_rowmap[M_ROWS];  // compact slot -> original row
__device__ int g_slot[M_ROWS];    // original row -> compact slot, or -1 if mask=0

__device__ __forceinline__ ushort f2bf(float f) {
  uint32_t u = __float_as_uint(f);
  u += 0x7FFFu + ((u >> 16) & 1u);
  return (ushort)(u >> 16);
}

__device__ __forceinline__ void gload_lds16(const void* g, void* l) {
  __builtin_amdgcn_global_load_lds((const __attribute__((address_space(1))) void*)g,
                                   (__attribute__((address_space(3))) void*)l, 16, 0, 0);
}

#define BARRIER()    asm volatile("s_barrier" ::: "memory")
#define WAIT_LGKM(n) asm volatile("s_waitcnt lgkmcnt(" #n ")" ::: "memory")
#define WAIT_VM(n)   asm volatile("s_waitcnt vmcnt(" #n ")" ::: "memory")

// ---------------- mask scan: isbool-detect + prefix scan -> rowmap/slot/meff ----------------
__global__ void scan_mask_kernel(const void* __restrict__ mask) {
  __shared__ int cnt[1024];
  const int t = threadIdx.x;
  const unsigned* mw = (const unsigned*)mask;
  int isbool = 0;
  for (int i = 0; i < 64; ++i)
    if (mw[i] & ~1u) isbool = 1;
  int pred[6]; int c = 0;
#pragma unroll
  for (int j = 0; j < 6; ++j) {
    const int m  = t * 6 + j;
    const int bb = (m >= ROWS_PB) ? 1 : 0;
    const int idx = bb * S_TOK + P_TOK + (m - bb * ROWS_PB);
    const int v = isbool ? (int)((const unsigned char*)mask)[idx]
                         : ((const int*)mask)[idx];
    pred[j] = (v != 0);
    c += pred[j];
  }
  cnt[t] = c;
  __syncthreads();
  for (int off = 1; off < 1024; off <<= 1) {
    const int v = (t >= off) ? cnt[t - off] : 0;
    __syncthreads();
    cnt[t] += v;
    __syncthreads();
  }
  int p = cnt[t] - c;               // exclusive prefix
  if (t == 1023) g_meff = cnt[1023];
#pragma unroll
  for (int j = 0; j < 6; ++j) {
    const int m = t * 6 + j;
    if (pred[j]) { g_rowmap[p] = m; g_slot[m] = p; ++p; }
    else         { g_slot[m] = -1; }
  }
}

// ------- fused prepass: per-row convert-or-zerofill (blocks 0..6143) + W1 transpose -------
__global__ void prepass_kernel(const float* __restrict__ x, ushort* __restrict__ A1,
                               const float* __restrict__ W1, ushort* __restrict__ W1T,
                               float* __restrict__ out) {
  __shared__ float tile[64][65];
  const int bid = blockIdx.x;
  const int t   = threadIdx.x;
  if (bid < M_ROWS) {
    const int slot = g_slot[bid];
    if (slot >= 0) {
      const int bb = (bid >= ROWS_PB) ? 1 : 0;
      const int s  = P_TOK + (bid - bb * ROWS_PB);
      const float* src = x + ((size_t)bb * S_TOK + s) * TEXT_H_;
      ushort* dst = A1 + (size_t)slot * TEXT_H_;
#pragma unroll
      for (int c = 0; c < 2; ++c) {
        const int base = t * 16 + c * 8;
        fl4_t f0 = *(const fl4_t*)(src + base);
        fl4_t f1 = *(const fl4_t*)(src + base + 4);
        u16x8_t o;
        o[0] = f2bf(f0[0]); o[1] = f2bf(f0[1]); o[2] = f2bf(f0[2]); o[3] = f2bf(f0[3]);
        o[4] = f2bf(f1[0]); o[5] = f2bf(f1[1]); o[6] = f2bf(f1[2]); o[7] = f2bf(f1[3]);
        *(u16x8_t*)(dst + base) = o;
      }
    } else {
      float* dst = out + (size_t)bid * NK + t * 16;
      const fl4_t z = {0.0f, 0.0f, 0.0f, 0.0f};
#pragma unroll
      for (int c = 0; c < 4; ++c) *(fl4_t*)(dst + c * 4) = z;
    }
  } else {
    const int tb = bid - M_ROWS;            // 0..4095
    const int kb = (tb & 63) * 64;
    const int nb = (tb >> 6) * 64;
    const int lr = t >> 4;
    const int lc = (t & 15) * 4;
#pragma unroll
    for (int it = 0; it < 4; ++it) {
      const int row = lr + it * 16;
      fl4_t v = *(const fl4_t*)(W1 + (size_t)(kb + row) * NK + nb + lc);
      tile[row][lc + 0] = v[0]; tile[row][lc + 1] = v[1];
      tile[row][lc + 2] = v[2]; tile[row][lc + 3] = v[3];
    }
    __syncthreads();
#pragma unroll
    for (int it = 0; it < 4; ++it) {
      const int n = lr + it * 16;
      u16x4_t o;
      o[0] = f2bf(tile[lc + 0][n]); o[1] = f2bf(tile[lc + 1][n]);
      o[2] = f2bf(tile[lc + 2][n]); o[3] = f2bf(tile[lc + 3][n]);
      *(u16x4_t*)(W1T + (size_t)(nb + n) * NK + kb + lc) = o;
    }
  }
}

// ===================== staging — BM=224 RACE-FIXED group map =====================
// chunk(blk,kk) = 1KB: rows blk*16..+15, k kk*32..+31; lane l <-> row blk*16+(l&15),
// k +(l>>4)*8. A: chunks 0..31, B: 32..63.
// BM=224 read sets: afL = blks {0-3}u{7-10} = chunks {0-7,14-21};
//                   afH = blks {4-6}u{11-13} = chunks {8-13,22-27}.
// Groups (16 chunks, 2 loads/thread) MATCH the read sets (r18 race fix):
//  J0 = chunks {0-7,14-21}  (exactly afL)     staged at P2 for tile t+2
//  J3 = chunks {8-13,22-31} (>= afH; 28-31 staged-unused) staged at P1 for tile t+1
//  J1 = B rel {0-3,8-11,16-19,24-27} (bfL)    staged at P3 for tile t+2
//  J2 = B rel {4-7,12-15,20-23,28-31} (bfH)   staged at P4 for tile t+2
template <int J>
__device__ __forceinline__ void stage_g0(const ushort* __restrict__ A,
                                         const ushort* __restrict__ Bt,
                                         int row0, int col0, char* lds,
                                         int tau, int w, int l) {
  char* slot = lds + (tau & 1) * SLOT0_BYTES;
  const int kt = tau * BK;
#pragma unroll
  for (int q = 0; q < 2; ++q) {
    const int cg = q * 8 + w;
    if (J == 0 || J == 3) {
      const int CH = (J == 0) ? ((cg < 8) ? cg : cg + 6)        // {0-7,14-21}
                              : ((cg < 6) ? cg + 8 : cg + 16);  // {8-13,22-31}
      const ushort* src = A + (size_t)(row0 + (CH >> 1) * 16 + (l & 15)) * NK
                            + kt + (CH & 1) * 32 + (l >> 4) * 8;
      gload_lds16(src, slot + CH * 1024 + l * 16);
    } else {
      const int r = (cg >> 2) * 8 + (cg & 3) + (J == 2 ? 4 : 0);
      const ushort* src = Bt + (size_t)(col0 + (r >> 1) * 16 + (l & 15)) * NK
                             + kt + (r & 1) * 32 + (l >> 4) * 8;
      gload_lds16(src, slot + (32 + r) * 1024 + l * 16);
    }
  }
}

// ---------------- compacted GEMM (r14 engine @ BM=224) + embedded W2-transpose ----------
// Wave output 112x64: afL rows wr*112+mi*16 (mi<4), afH +64 (mi<3). Quadrants
// LL(16) LH(16) HL(12) HH(12). lgkm ledger: P1(4), P2(6), P3(8 / 0 at tail), P4 none.
// Staging guarantee chain (re-verified for new groups): J3(t)+J0(t+1) land at
// P4(t-1)'s VM(4)+barrier -> P2(t) afH reads and P3(t) afL refills are safe.
template <int MODE>
__launch_bounds__(512, 2)
__global__ void gemm_c_kernel(const ushort* __restrict__ A, const ushort* __restrict__ Bt,
                              const float* __restrict__ bias,
                              const float* __restrict__ Wsrc, ushort* __restrict__ Wdst,
                              ushort* __restrict__ Hout, float* __restrict__ Yout) {
  extern __shared__ char lds[];
  const int tid = threadIdx.x;

  const int orig = blockIdx.x;
  if (MODE == 0 && orig >= NWGC) {
    // ---- W2 transpose worker: 32 blocks x 2 panels (512 thr = 2x256), 64 k-tiles each ----
    const int tw   = orig - NWGC;           // 0..31
    const int half = tid >> 8;              // 0/1 -> panel tw / tw+32
    const int ht   = tid & 255;
    float (*tile)[65] = (float(*)[65])(lds + half * 20480);
    const int nb = (tw + half * 32) * 64;
    const int lr = ht >> 4;
    const int lc = (ht & 15) * 4;
    for (int i = 0; i < 64; ++i) {
      const int kb = i * 64;
#pragma unroll
      for (int it = 0; it < 4; ++it) {
        const int row = lr + it * 16;
        fl4_t v = *(const fl4_t*)(Wsrc + (size_t)(kb + row) * NK + nb + lc);
        tile[row][lc + 0] = v[0]; tile[row][lc + 1] = v[1];
        tile[row][lc + 2] = v[2]; tile[row][lc + 3] = v[3];
      }
      __syncthreads();
#pragma unroll
      for (int it = 0; it < 4; ++it) {
        const int n = lr + it * 16;
        u16x4_t o;
        o[0] = f2bf(tile[lc + 0][n]); o[1] = f2bf(tile[lc + 1][n]);
        o[2] = f2bf(tile[lc + 2][n]); o[3] = f2bf(tile[lc + 3][n]);
        *(u16x4_t*)(Wdst + (size_t)(nb + n) * NK + kb + lc) = o;
      }
      __syncthreads();
    }
    return;
  }

  const int l   = tid & 63;
  const int w   = tid >> 6;
  const int wr  = w >> 2;         // 0..1: rows wr*112
  const int wc  = w & 3;          // 0..3: cols wc*64

  const int meff = g_meff;
  const int mt   = (meff + BM0 - 1) / BM0;   // active M-tiles (<=14 for meff<=3136)
  const int nact = mt * 16;                  // active blocks; %8 == 0

  if (orig >= nact) return;
  const int bid  = (orig & 7) * (nact >> 3) + (orig >> 3);  // meff-aware XCD swizzle (r11)
  const int row0 = (bid >> 4) * BM0;
  const int col0 = (bid & 15) * BN;

  f32x4_t acc[7][4] = {};

  stage_g0<0>(A, Bt, row0, col0, lds, 0, w, l);
  stage_g0<1>(A, Bt, row0, col0, lds, 0, w, l);
  stage_g0<2>(A, Bt, row0, col0, lds, 0, w, l);
  stage_g0<3>(A, Bt, row0, col0, lds, 0, w, l);
  stage_g0<0>(A, Bt, row0, col0, lds, 1, w, l);
  stage_g0<1>(A, Bt, row0, col0, lds, 1, w, l);
  stage_g0<2>(A, Bt, row0, col0, lds, 1, w, l);
  WAIT_VM(4);                      // tile0 (J0-J3) + J0(1) landed; [J1(1),J2(1)] in flight
  BARRIER();                       // publication barrier

  // prologue reads: afL/bfL of tile 0 (12 in flight; drained at P1(0)'s lgkm(4))
  bf16x8_t afL[4][2], bfL[2][2], afH[3][2], bfH[2][2];
#pragma unroll
  for (int mi = 0; mi < 4; ++mi)
#pragma unroll
    for (int kk = 0; kk < 2; ++kk)
      afL[mi][kk] = *(const bf16x8_t*)(lds + (2 * (wr * 7 + mi) + kk) * 1024 + l * 16);
#pragma unroll
  for (int ni = 0; ni < 2; ++ni)
#pragma unroll
    for (int kk = 0; kk < 2; ++kk)
      bfL[ni][kk] = *(const bf16x8_t*)(lds + (32 + 2 * (wc * 4 + ni) + kk) * 1024 + l * 16);

  for (int t = 0; t < NT; ++t) {
    char* s  = lds + (t & 1) * SLOT0_BYTES;
    char* sn = lds + ((t + 1) & 1) * SLOT0_BYTES;

    // ---- P1: issue bfH(4); stage J3(t+1); lgkm(4); MFMA LL (16) ----
#pragma unroll
    for (int ni = 0; ni < 2; ++ni)
#pragma unroll
      for (int kk = 0; kk < 2; ++kk)
        bfH[ni][kk] = *(const bf16x8_t*)(s + (32 + 2 * (wc * 4 + 2 + ni) + kk) * 1024 + l * 16);
    if (t + 1 < NT) stage_g0<3>(A, Bt, row0, col0, lds, t + 1, w, l);
    WAIT_LGKM(4);
    __builtin_amdgcn_s_setprio(1);
#pragma unroll
    for (int mi = 0; mi < 4; ++mi)
#pragma unroll
      for (int ni = 0; ni < 2; ++ni)
#pragma unroll
        for (int kk = 0; kk < 2; ++kk)
          acc[mi][ni] = __builtin_amdgcn_mfma_f32_16x16x32_bf16(afL[mi][kk], bfL[ni][kk],
                                                                acc[mi][ni], 0, 0, 0);
    __builtin_amdgcn_s_setprio(0);
    BARRIER();   // end-P1

    // ---- P2: issue afH(6, rows +64, mi<3); stage J0(t+2); lgkm(6); MFMA LH (16) ----
#pragma unroll
    for (int mi = 0; mi < 3; ++mi)
#pragma unroll
      for (int kk = 0; kk < 2; ++kk)
        afH[mi][kk] = *(const bf16x8_t*)(s + (2 * (wr * 7 + 4 + mi) + kk) * 1024 + l * 16);
    if (t + 2 < NT) stage_g0<0>(A, Bt, row0, col0, lds, t + 2, w, l);
    WAIT_LGKM(6);
    __builtin_amdgcn_s_setprio(1);
#pragma unroll
    for (int mi = 0; mi < 4; ++mi)
#pragma unroll
      for (int ni = 0; ni < 2; ++ni)
#pragma unroll
        for (int kk = 0; kk < 2; ++kk)
          acc[mi][2 + ni] = __builtin_amdgcn_mfma_f32_16x16x32_bf16(afL[mi][kk], bfH[ni][kk],
                                                                    acc[mi][2 + ni], 0, 0, 0);
    __builtin_amdgcn_s_setprio(0);
    BARRIER();   // end-P2

    // ---- P3: refill afL <- t+1 J0 (8); stage J1(t+2); lgkm(8) drains afH; MFMA HL (12) ----
    if (t + 1 < NT) {
#pragma unroll
      for (int mi = 0; mi < 4; ++mi)
#pragma unroll
        for (int kk = 0; kk < 2; ++kk)
          afL[mi][kk] = *(const bf16x8_t*)(sn + (2 * (wr * 7 + mi) + kk) * 1024 + l * 16);
    }
    if (t + 2 < NT) stage_g0<1>(A, Bt, row0, col0, lds, t + 2, w, l);
    if (t + 1 < NT) { WAIT_LGKM(8); } else { WAIT_LGKM(0); }
    __builtin_amdgcn_s_setprio(1);
#pragma unroll
    for (int mi = 0; mi < 3; ++mi)
#pragma unroll
      for (int ni = 0; ni < 2; ++ni)
#pragma unroll
        for (int kk = 0; kk < 2; ++kk)
          acc[4 + mi][ni] = __builtin_amdgcn_mfma_f32_16x16x32_bf16(afH[mi][kk], bfL[ni][kk],
                                                                    acc[4 + mi][ni], 0, 0, 0);
    __builtin_amdgcn_s_setprio(0);
    BARRIER();   // end-P3

    // ---- P4: stage J2(t+2); VM(4); publication barrier; refill bfL <- t+1 J1; MFMA HH (12) ----
    if (t + 2 < NT) stage_g0<2>(A, Bt, row0, col0, lds, t + 2, w, l);
    if (t >= NT - 2) { WAIT_VM(0); } else { WAIT_VM(4); }
    BARRIER();   // cross-wave DMA publication
    if (t + 1 < NT) {
#pragma unroll
      for (int ni = 0; ni < 2; ++ni)
#pragma unroll
        for (int kk = 0; kk < 2; ++kk)
          bfL[ni][kk] = *(const bf16x8_t*)(sn + (32 + 2 * (wc * 4 + ni) + kk) * 1024 + l * 16);
    }
    __builtin_amdgcn_s_setprio(1);
#pragma unroll
    for (int mi = 0; mi < 3; ++mi)
#pragma unroll
      for (int ni = 0; ni < 2; ++ni)
#pragma unroll
        for (int kk = 0; kk < 2; ++kk)
          acc[4 + mi][2 + ni] = __builtin_amdgcn_mfma_f32_16x16x32_bf16(afH[mi][kk], bfH[ni][kk],
                                                                        acc[4 + mi][2 + ni], 0, 0, 0);
    __builtin_amdgcn_s_setprio(0);
    BARRIER();   // end-P4
  }

  // epilogue: rows wr*112 + mi*16 + (l>>4)*4 + j, mi<7; D col = lane&15 (r3-r17 verified)
#pragma unroll
  for (int mi = 0; mi < 7; ++mi) {
#pragma unroll
    for (int j = 0; j < 4; ++j) {
      const int r = row0 + wr * 112 + mi * 16 + (l >> 4) * 4 + j;
      if (MODE == 0) {
#pragma unroll
        for (int ni = 0; ni < 4; ++ni) {
          const int c = col0 + wc * 64 + ni * 16 + (l & 15);
          float v = acc[mi][ni][j] + bias[c];
          v = 0.5f * v * (1.0f + erff(v * 0.70710678118654752f));
          Hout[(size_t)r * NK + c] = f2bf(v);
        }
      } else {
        if (r < meff) {
          const int orig_row = g_rowmap[r];
          float* dst = Yout + (size_t)orig_row * NK;
#pragma unroll
          for (int ni = 0; ni < 4; ++ni) {
            const int c = col0 + wc * 64 + ni * 16 + (l & 15);
            dst[c] = acc[mi][ni][j] + bias[c];
          }
        }
      }
    }
  }
}

extern "C" void kernel_launch(void* const* d_in, const int* in_sizes, int n_in,
                              void* d_out, int out_size, void* d_ws, size_t ws_size,
                              hipStream_t stream) {
  const float* x     = (const float*)d_in[0];
  const void*  tmask = (const void*)d_in[1];
  // d_in[2] = prefix_mask (shape known: prefix_len = 4096 rows dropped)
  const float* W1    = (const float*)d_in[3];
  const float* b1    = (const float*)d_in[4];
  const float* W2    = (const float*)d_in[5];
  const float* b2    = (const float*)d_in[6];
  float* out = (float*)d_out;   // reference output dtype is float32

  const size_t offA1  = 0;
  const size_t offB1T = offA1  + (size_t)M_ROWS * NK * 2;   // 48 MiB
  const size_t offB2T = offB1T + (size_t)NK * NK * 2;       // +32 MiB
  const size_t offH   = offB2T + (size_t)NK * NK * 2;       // +32 MiB
  const size_t need   = offH   + (size_t)M_ROWS * NK * 2;   // +48 MiB = 160 MiB
  if (ws_size < need) return;

  char* ws = (char*)d_ws;
  ushort* A1  = (ushort*)(ws + offA1);
  ushort* B1T = (ushort*)(ws + offB1T);
  ushort* B2T = (ushort*)(ws + offB2T);
  ushort* H   = (ushort*)(ws + offH);

  // 1. scan mask -> meff/rowmap/slot
  scan_mask_kernel<<<dim3(1), dim3(1024), 0, stream>>>(tmask);
  // 2. fused prepass: convert mask=1 rows -> A1, zero-fill mask=0 out rows, transpose W1
  prepass_kernel<<<dim3(M_ROWS + 4096), dim3(256), 0, stream>>>(x, A1, W1, B1T, out);
  // 3. GEMM1 (+32 embedded dual-panel W2-transpose blocks; residency <= 256)
  gemm_c_kernel<0><<<dim3(NWGC + TW2_BLKS), dim3(512), LDS0_TOTAL, stream>>>(
      A1, B1T, b1, W2, B2T, H, nullptr);
  // 4. GEMM2 (scatter to mask=1 rows; mask=0 rows already zeroed by prepass)
  gemm_c_kernel<1><<<dim3(NWGC), dim3(512), LDS0_TOTAL, stream>>>(
      H, B2T, b2, nullptr, nullptr, nullptr, out);
}

// Round 20
// 334.012 us; speedup vs baseline: 1.2540x; 1.2540x over previous
//
#include <hip/hip_runtime.h>
#include <hip/hip_bf16.h>
#include <cstdint>
#include <cstddef>

#define TEXT_H_   4096
#define S_TOK     4096
#define P_TOK     1024
#define ROWS_PB   3072            // rows per batch after dropping s<1024
#define M_ROWS    6144            // 2 * 3072
#define NK        4096            // N and K of both GEMMs
#define BK        64
#define NT        (NK / BK)       // 64 K-tiles

// compacted GEMM: 256x256 tile, 8 waves, 4-phase/K-tile (r14-verified engine)
#define BM0       256
#define BN        256
#define NWGC      384             // worst-case 24 M-tiles x 16 N-tiles
#define TW2_BLKS  64              // extra blocks in GEMM1 that transpose W2
#define SLOT0_BYTES (64 * 1024)
#define LDS0_TOTAL  (2 * SLOT0_BYTES)

typedef __attribute__((ext_vector_type(8))) short  bf16x8_t;
typedef __attribute__((ext_vector_type(4))) float  f32x4_t;
typedef __attribute__((ext_vector_type(4))) float  fl4_t;
typedef __attribute__((ext_vector_type(4))) ushort u16x4_t;
typedef __attribute__((ext_vector_type(8))) ushort u16x8_t;

__device__ int g_meff;            // number of masked (active) rows
__device__ int g_rowmap[M_ROWS];  // compact slot -> original row
__device__ int g_slot[M_ROWS];    // original row -> compact slot, or -1 if mask=0

__device__ __forceinline__ ushort f2bf(float f) {
  uint32_t u = __float_as_uint(f);
  u += 0x7FFFu + ((u >> 16) & 1u);
  return (ushort)(u >> 16);
}

__device__ __forceinline__ void gload_lds16(const void* g, void* l) {
  __builtin_amdgcn_global_load_lds((const __attribute__((address_space(1))) void*)g,
                                   (__attribute__((address_space(3))) void*)l, 16, 0, 0);
}

#define BARRIER()    asm volatile("s_barrier" ::: "memory")
#define WAIT_LGKM(n) asm volatile("s_waitcnt lgkmcnt(" #n ")" ::: "memory")
#define WAIT_VM(n)   asm volatile("s_waitcnt vmcnt(" #n ")" ::: "memory")

// ---------------- mask scan: isbool-detect + prefix scan -> rowmap/slot/meff ----------------
__global__ void scan_mask_kernel(const void* __restrict__ mask) {
  __shared__ int cnt[1024];
  const int t = threadIdx.x;
  const unsigned* mw = (const unsigned*)mask;
  int isbool = 0;
  for (int i = 0; i < 64; ++i)
    if (mw[i] & ~1u) isbool = 1;
  int pred[6]; int c = 0;
#pragma unroll
  for (int j = 0; j < 6; ++j) {
    const int m  = t * 6 + j;
    const int bb = (m >= ROWS_PB) ? 1 : 0;
    const int idx = bb * S_TOK + P_TOK + (m - bb * ROWS_PB);
    const int v = isbool ? (int)((const unsigned char*)mask)[idx]
                         : ((const int*)mask)[idx];
    pred[j] = (v != 0);
    c += pred[j];
  }
  cnt[t] = c;
  __syncthreads();
  for (int off = 1; off < 1024; off <<= 1) {
    const int v = (t >= off) ? cnt[t - off] : 0;
    __syncthreads();
    cnt[t] += v;
    __syncthreads();
  }
  int p = cnt[t] - c;               // exclusive prefix
  if (t == 1023) g_meff = cnt[1023];
#pragma unroll
  for (int j = 0; j < 6; ++j) {
    const int m = t * 6 + j;
    if (pred[j]) { g_rowmap[p] = m; g_slot[m] = p; ++p; }
    else         { g_slot[m] = -1; }
  }
}

// ------- fused prepass: per-row convert-or-zerofill (blocks 0..6143) + W1 transpose -------
// block m < M_ROWS: mask=1 -> A1[slot] = bf16(x row); mask=0 -> out[m*4096..+4096) = 0
// block >= M_ROWS: W1 64x64 transpose tile tb = bid - M_ROWS (4096 tiles)
__global__ void prepass_kernel(const float* __restrict__ x, ushort* __restrict__ A1,
                               const float* __restrict__ W1, ushort* __restrict__ W1T,
                               float* __restrict__ out) {
  __shared__ float tile[64][65];
  const int bid = blockIdx.x;
  const int t   = threadIdx.x;
  if (bid < M_ROWS) {
    const int slot = g_slot[bid];
    if (slot >= 0) {
      const int bb = (bid >= ROWS_PB) ? 1 : 0;
      const int s  = P_TOK + (bid - bb * ROWS_PB);
      const float* src = x + ((size_t)bb * S_TOK + s) * TEXT_H_;
      ushort* dst = A1 + (size_t)slot * TEXT_H_;
#pragma unroll
      for (int c = 0; c < 2; ++c) {
        const int base = t * 16 + c * 8;
        fl4_t f0 = *(const fl4_t*)(src + base);
        fl4_t f1 = *(const fl4_t*)(src + base + 4);
        u16x8_t o;
        o[0] = f2bf(f0[0]); o[1] = f2bf(f0[1]); o[2] = f2bf(f0[2]); o[3] = f2bf(f0[3]);
        o[4] = f2bf(f1[0]); o[5] = f2bf(f1[1]); o[6] = f2bf(f1[2]); o[7] = f2bf(f1[3]);
        *(u16x8_t*)(dst + base) = o;
      }
    } else {
      float* dst = out + (size_t)bid * NK + t * 16;
      const fl4_t z = {0.0f, 0.0f, 0.0f, 0.0f};
#pragma unroll
      for (int c = 0; c < 4; ++c) *(fl4_t*)(dst + c * 4) = z;
    }
  } else {
    const int tb = bid - M_ROWS;            // 0..4095
    const int kb = (tb & 63) * 64;
    const int nb = (tb >> 6) * 64;
    const int lr = t >> 4;
    const int lc = (t & 15) * 4;
#pragma unroll
    for (int it = 0; it < 4; ++it) {
      const int row = lr + it * 16;
      fl4_t v = *(const fl4_t*)(W1 + (size_t)(kb + row) * NK + nb + lc);
      tile[row][lc + 0] = v[0]; tile[row][lc + 1] = v[1];
      tile[row][lc + 2] = v[2]; tile[row][lc + 3] = v[3];
    }
    __syncthreads();
#pragma unroll
    for (int it = 0; it < 4; ++it) {
      const int n = lr + it * 16;
      u16x4_t o;
      o[0] = f2bf(tile[lc + 0][n]); o[1] = f2bf(tile[lc + 1][n]);
      o[2] = f2bf(tile[lc + 2][n]); o[3] = f2bf(tile[lc + 3][n]);
      *(u16x4_t*)(W1T + (size_t)(nb + n) * NK + kb + lc) = o;
    }
  }
}

// ===================== staging (r8-r14 proven chunk map + protocol) =====================
// chunk(blk,kk) = 1KB: rows blk*16..+15, k kk*32..+31; lane l <-> row blk*16+(l&15),
// k +(l>>4)*8. A: chunks 0..31, B: 32..63. Groups of 16 chunks (2 loads/thread):
//  J0: A {0-7,16-23} (afL)  J1: B rel {0-3,8-11,16-19,24-27} (bfL, all wc)
//  J2: B rel {4-7,12-15,20-23,28-31} (bfH, all wc)  J3: A {8-15,24-31} (afH)
template <int J>
__device__ __forceinline__ void stage_g0(const ushort* __restrict__ A,
                                         const ushort* __restrict__ Bt,
                                         int row0, int col0, char* lds,
                                         int tau, int w, int l) {
  char* slot = lds + (tau & 1) * SLOT0_BYTES;
  const int kt = tau * BK;
#pragma unroll
  for (int q = 0; q < 2; ++q) {
    const int cg = q * 8 + w;
    if (J == 0 || J == 3) {
      const int CH = (J == 0 ? 0 : 8) + cg + (cg & 8);
      const ushort* src = A + (size_t)(row0 + (CH >> 1) * 16 + (l & 15)) * NK
                            + kt + (CH & 1) * 32 + (l >> 4) * 8;
      gload_lds16(src, slot + CH * 1024 + l * 16);
    } else {
      const int r = (cg >> 2) * 8 + (cg & 3) + (J == 2 ? 4 : 0);
      const ushort* src = Bt + (size_t)(col0 + (r >> 1) * 16 + (l & 15)) * NK
                             + kt + (r & 1) * 32 + (l >> 4) * 8;
      gload_lds16(src, slot + (32 + r) * 1024 + l * 16);
    }
  }
}

// ---------------- compacted GEMM (r14 engine) + embedded W2-transpose blocks ----------
// MODE 0: Hout[r_c][c] = bf16(gelu(acc+bias)); blocks >= NWGC transpose W2 -> Wdst.
// MODE 1: Yout[g_rowmap[r_c]*4096+c] = f32(acc+bias) for r_c < g_meff (scatter).
template <int MODE>
__launch_bounds__(512, 2)
__global__ void gemm_c_kernel(const ushort* __restrict__ A, const ushort* __restrict__ Bt,
                              const float* __restrict__ bias,
                              const float* __restrict__ Wsrc, ushort* __restrict__ Wdst,
                              ushort* __restrict__ Hout, float* __restrict__ Yout) {
  extern __shared__ char lds[];
  const int tid = threadIdx.x;

  const int orig = blockIdx.x;
  if (MODE == 0 && orig >= NWGC) {
    // ---- W2 transpose worker: block tw handles tiles tb = tw + 64*i (col nb fixed) ----
    const int tw = orig - NWGC;             // 0..63
    float (*tile)[65] = (float(*)[65])lds;  // 16.6KB of the 128KB dynamic LDS
    const int nb = tw * 64;
    const int lr = tid >> 4;                // only tid<256 work
    const int lc = (tid & 15) * 4;
    for (int i = 0; i < 64; ++i) {
      const int kb = i * 64;
      if (tid < 256) {
#pragma unroll
        for (int it = 0; it < 4; ++it) {
          const int row = lr + it * 16;
          fl4_t v = *(const fl4_t*)(Wsrc + (size_t)(kb + row) * NK + nb + lc);
          tile[row][lc + 0] = v[0]; tile[row][lc + 1] = v[1];
          tile[row][lc + 2] = v[2]; tile[row][lc + 3] = v[3];
        }
      }
      __syncthreads();
      if (tid < 256) {
#pragma unroll
        for (int it = 0; it < 4; ++it) {
          const int n = lr + it * 16;
          u16x4_t o;
          o[0] = f2bf(tile[lc + 0][n]); o[1] = f2bf(tile[lc + 1][n]);
          o[2] = f2bf(tile[lc + 2][n]); o[3] = f2bf(tile[lc + 3][n]);
          *(u16x4_t*)(Wdst + (size_t)(nb + n) * NK + kb + lc) = o;
        }
      }
      __syncthreads();
    }
    return;
  }

  const int l   = tid & 63;
  const int w   = tid >> 6;
  const int wr  = w >> 2;         // 0..1: rows wr*128
  const int wc  = w & 3;          // 0..3: cols wc*64

  const int meff = g_meff;
  const int mt   = (meff + BM0 - 1) / BM0;   // active M-tiles
  const int nact = mt * 16;                  // active blocks; mt*16 % 8 == 0

  if (orig >= nact) return;                  // inactive blocks retire immediately
  const int bid  = (orig & 7) * (nact >> 3) + (orig >> 3);  // meff-aware XCD swizzle (r11)
  const int row0 = (bid >> 4) * BM0;
  const int col0 = (bid & 15) * BN;

  f32x4_t acc[8][4] = {};

  stage_g0<0>(A, Bt, row0, col0, lds, 0, w, l);
  stage_g0<1>(A, Bt, row0, col0, lds, 0, w, l);
  stage_g0<2>(A, Bt, row0, col0, lds, 0, w, l);
  stage_g0<3>(A, Bt, row0, col0, lds, 0, w, l);
  stage_g0<0>(A, Bt, row0, col0, lds, 1, w, l);
  stage_g0<1>(A, Bt, row0, col0, lds, 1, w, l);
  stage_g0<2>(A, Bt, row0, col0, lds, 1, w, l);
  WAIT_VM(4);                      // tile0 + J0(1) landed
  BARRIER();                       // publication barrier

  // prologue reads: afL/bfL of tile 0 (drained at P1(0)'s lgkm(4))
  bf16x8_t afL[4][2], bfL[2][2], afH[4][2], bfH[2][2];
#pragma unroll
  for (int mi = 0; mi < 4; ++mi)
#pragma unroll
    for (int kk = 0; kk < 2; ++kk)
      afL[mi][kk] = *(const bf16x8_t*)(lds + (2 * (wr * 8 + mi) + kk) * 1024 + l * 16);
#pragma unroll
  for (int ni = 0; ni < 2; ++ni)
#pragma unroll
    for (int kk = 0; kk < 2; ++kk)
      bfL[ni][kk] = *(const bf16x8_t*)(lds + (32 + 2 * (wc * 4 + ni) + kk) * 1024 + l * 16);

  for (int t = 0; t < NT; ++t) {
    char* s  = lds + (t & 1) * SLOT0_BYTES;
    char* sn = lds + ((t + 1) & 1) * SLOT0_BYTES;

    // ---- P1: issue bfH(4); stage J3(t+1); lgkm(4); MFMA LL ----
#pragma unroll
    for (int ni = 0; ni < 2; ++ni)
#pragma unroll
      for (int kk = 0; kk < 2; ++kk)
        bfH[ni][kk] = *(const bf16x8_t*)(s + (32 + 2 * (wc * 4 + 2 + ni) + kk) * 1024 + l * 16);
    if (t + 1 < NT) stage_g0<3>(A, Bt, row0, col0, lds, t + 1, w, l);
    WAIT_LGKM(4);
    __builtin_amdgcn_s_setprio(1);
#pragma unroll
    for (int mi = 0; mi < 4; ++mi)
#pragma unroll
      for (int ni = 0; ni < 2; ++ni)
#pragma unroll
        for (int kk = 0; kk < 2; ++kk)
          acc[mi][ni] = __builtin_amdgcn_mfma_f32_16x16x32_bf16(afL[mi][kk], bfL[ni][kk],
                                                                acc[mi][ni], 0, 0, 0);
    __builtin_amdgcn_s_setprio(0);
    BARRIER();   // end-P1

    // ---- P2: issue afH(8); stage J0(t+2); lgkm(8); MFMA LH (afL dies) ----
#pragma unroll
    for (int mi = 0; mi < 4; ++mi)
#pragma unroll
      for (int kk = 0; kk < 2; ++kk)
        afH[mi][kk] = *(const bf16x8_t*)(s + (2 * (wr * 8 + 4 + mi) + kk) * 1024 + l * 16);
    if (t + 2 < NT) stage_g0<0>(A, Bt, row0, col0, lds, t + 2, w, l);
    WAIT_LGKM(8);
    __builtin_amdgcn_s_setprio(1);
#pragma unroll
    for (int mi = 0; mi < 4; ++mi)
#pragma unroll
      for (int ni = 0; ni < 2; ++ni)
#pragma unroll
        for (int kk = 0; kk < 2; ++kk)
          acc[mi][2 + ni] = __builtin_amdgcn_mfma_f32_16x16x32_bf16(afL[mi][kk], bfH[ni][kk],
                                                                    acc[mi][2 + ni], 0, 0, 0);
    __builtin_amdgcn_s_setprio(0);
    BARRIER();   // end-P2

    // ---- P3: refill afL <- t+1 J0 (8); stage J1(t+2); lgkm(8); MFMA HL (bfL dies) ----
    if (t + 1 < NT) {
#pragma unroll
      for (int mi = 0; mi < 4; ++mi)
#pragma unroll
        for (int kk = 0; kk < 2; ++kk)
          afL[mi][kk] = *(const bf16x8_t*)(sn + (2 * (wr * 8 + mi) + kk) * 1024 + l * 16);
    }
    if (t + 2 < NT) stage_g0<1>(A, Bt, row0, col0, lds, t + 2, w, l);
    if (t + 1 < NT) { WAIT_LGKM(8); } else { WAIT_LGKM(0); }
    __builtin_amdgcn_s_setprio(1);
#pragma unroll
    for (int mi = 0; mi < 4; ++mi)
#pragma unroll
      for (int ni = 0; ni < 2; ++ni)
#pragma unroll
        for (int kk = 0; kk < 2; ++kk)
          acc[4 + mi][ni] = __builtin_amdgcn_mfma_f32_16x16x32_bf16(afH[mi][kk], bfL[ni][kk],
                                                                    acc[4 + mi][ni], 0, 0, 0);
    __builtin_amdgcn_s_setprio(0);
    BARRIER();   // end-P3

    // ---- P4: stage J2(t+2); VM(4); publication barrier; refill bfL <- t+1 J1; MFMA HH ----
    if (t + 2 < NT) stage_g0<2>(A, Bt, row0, col0, lds, t + 2, w, l);
    if (t >= NT - 2) { WAIT_VM(0); } else { WAIT_VM(4); }
    BARRIER();   // cross-wave DMA publication
    if (t + 1 < NT) {
#pragma unroll
      for (int ni = 0; ni < 2; ++ni)
#pragma unroll
        for (int kk = 0; kk < 2; ++kk)
          bfL[ni][kk] = *(const bf16x8_t*)(sn + (32 + 2 * (wc * 4 + ni) + kk) * 1024 + l * 16);
    }
    __builtin_amdgcn_s_setprio(1);
#pragma unroll
    for (int mi = 0; mi < 4; ++mi)
#pragma unroll
      for (int ni = 0; ni < 2; ++ni)
#pragma unroll
        for (int kk = 0; kk < 2; ++kk)
          acc[4 + mi][2 + ni] = __builtin_amdgcn_mfma_f32_16x16x32_bf16(afH[mi][kk], bfH[ni][kk],
                                                                        acc[4 + mi][2 + ni], 0, 0, 0);
    __builtin_amdgcn_s_setprio(0);
    BARRIER();   // end-P4
  }

  // epilogue: D col = lane&15, row = (lane>>4)*4 + j  (r3/r5/r9/r11-verified)
#pragma unroll
  for (int mi = 0; mi < 8; ++mi) {
#pragma unroll
    for (int j = 0; j < 4; ++j) {
      const int r = row0 + wr * 128 + mi * 16 + (l >> 4) * 4 + j;
      if (MODE == 0) {
#pragma unroll
        for (int ni = 0; ni < 4; ++ni) {
          const int c = col0 + wc * 64 + ni * 16 + (l & 15);
          float v = acc[mi][ni][j] + bias[c];
          v = 0.5f * v * (1.0f + erff(v * 0.70710678118654752f));
          Hout[(size_t)r * NK + c] = f2bf(v);
        }
      } else {
        if (r < meff) {                       // guard: rowmap beyond meff is undefined
          const int orig_row = g_rowmap[r];
          float* dst = Yout + (size_t)orig_row * NK;
#pragma unroll
          for (int ni = 0; ni < 4; ++ni) {
            const int c = col0 + wc * 64 + ni * 16 + (l & 15);
            dst[c] = acc[mi][ni][j] + bias[c];
          }
        }
      }
    }
  }
}

extern "C" void kernel_launch(void* const* d_in, const int* in_sizes, int n_in,
                              void* d_out, int out_size, void* d_ws, size_t ws_size,
                              hipStream_t stream) {
  const float* x     = (const float*)d_in[0];
  const void*  tmask = (const void*)d_in[1];
  // d_in[2] = prefix_mask (shape known: prefix_len = 4096 rows dropped)
  const float* W1    = (const float*)d_in[3];
  const float* b1    = (const float*)d_in[4];
  const float* W2    = (const float*)d_in[5];
  const float* b2    = (const float*)d_in[6];
  float* out = (float*)d_out;   // reference output dtype is float32

  const size_t offA1  = 0;
  const size_t offB1T = offA1  + (size_t)M_ROWS * NK * 2;   // 48 MiB
  const size_t offB2T = offB1T + (size_t)NK * NK * 2;       // +32 MiB
  const size_t offH   = offB2T + (size_t)NK * NK * 2;       // +32 MiB
  const size_t need   = offH   + (size_t)M_ROWS * NK * 2;   // +48 MiB = 160 MiB
  if (ws_size < need) return;

  char* ws = (char*)d_ws;
  ushort* A1  = (ushort*)(ws + offA1);
  ushort* B1T = (ushort*)(ws + offB1T);
  ushort* B2T = (ushort*)(ws + offB2T);
  ushort* H   = (ushort*)(ws + offH);

  // 1. scan mask -> meff/rowmap/slot
  scan_mask_kernel<<<dim3(1), dim3(1024), 0, stream>>>(tmask);
  // 2. fused prepass: convert mask=1 rows -> A1, zero-fill mask=0 out rows, transpose W1
  prepass_kernel<<<dim3(M_ROWS + 4096), dim3(256), 0, stream>>>(x, A1, W1, B1T, out);
  // 3. GEMM1 (+64 embedded W2-transpose blocks on otherwise-idle CUs)
  gemm_c_kernel<0><<<dim3(NWGC + TW2_BLKS), dim3(512), LDS0_TOTAL, stream>>>(
      A1, B1T, b1, W2, B2T, H, nullptr);
  // 4. GEMM2 (scatter to mask=1 rows; mask=0 rows already zeroed by prepass)
  gemm_c_kernel<1><<<dim3(NWGC), dim3(512), LDS0_TOTAL, stream>>>(
      H, B2T, b2, nullptr, nullptr, nullptr, out);
}

// Round 21
// 328.329 us; speedup vs baseline: 1.2757x; 1.0173x over previous
//
#include <hip/hip_runtime.h>
#include <hip/hip_bf16.h>
#include <cstdint>
#include <cstddef>

#define TEXT_H_   4096
#define S_TOK     4096
#define P_TOK     1024
#define ROWS_PB   3072            // rows per batch after dropping s<1024
#define M_ROWS    6144            // 2 * 3072
#define NK        4096            // N and K of both GEMMs
#define BK        64
#define NT        (NK / BK)       // 64 K-tiles

// compacted GEMM: 256x256 tile, 8 waves, 4-phase/K-tile (r14-verified engine)
#define BM0       256
#define BN        256
#define NWGC      384             // worst-case 24 M-tiles x 16 N-tiles
#define TW2_BLKS  32              // dual-panel W2-transpose blocks inside GEMM1 (512 thr = 2 panels)
#define SLOT0_BYTES (64 * 1024)
#define LDS0_TOTAL  (2 * SLOT0_BYTES)

typedef __attribute__((ext_vector_type(8))) short  bf16x8_t;
typedef __attribute__((ext_vector_type(4))) float  f32x4_t;
typedef __attribute__((ext_vector_type(4))) float  fl4_t;
typedef __attribute__((ext_vector_type(4))) ushort u16x4_t;
typedef __attribute__((ext_vector_type(8))) ushort u16x8_t;

__device__ int g_meff;            // number of masked (active) rows
__device__ int g_rowmap[M_ROWS];  // compact slot -> original row
__device__ int g_slot[M_ROWS];    // original row -> compact slot, or -1 if mask=0

__device__ __forceinline__ ushort f2bf(float f) {
  uint32_t u = __float_as_uint(f);
  u += 0x7FFFu + ((u >> 16) & 1u);
  return (ushort)(u >> 16);
}

__device__ __forceinline__ void gload_lds16(const void* g, void* l) {
  __builtin_amdgcn_global_load_lds((const __attribute__((address_space(1))) void*)g,
                                   (__attribute__((address_space(3))) void*)l, 16, 0, 0);
}

#define BARRIER()    asm volatile("s_barrier" ::: "memory")
#define WAIT_LGKM(n) asm volatile("s_waitcnt lgkmcnt(" #n ")" ::: "memory")
#define WAIT_VM(n)   asm volatile("s_waitcnt vmcnt(" #n ")" ::: "memory")

// ---------------- mask scan: isbool-detect + prefix scan -> rowmap/slot/meff ----------------
__global__ void scan_mask_kernel(const void* __restrict__ mask) {
  __shared__ int cnt[1024];
  const int t = threadIdx.x;
  const unsigned* mw = (const unsigned*)mask;
  int isbool = 0;
  for (int i = 0; i < 64; ++i)
    if (mw[i] & ~1u) isbool = 1;
  int pred[6]; int c = 0;
#pragma unroll
  for (int j = 0; j < 6; ++j) {
    const int m  = t * 6 + j;
    const int bb = (m >= ROWS_PB) ? 1 : 0;
    const int idx = bb * S_TOK + P_TOK + (m - bb * ROWS_PB);
    const int v = isbool ? (int)((const unsigned char*)mask)[idx]
                         : ((const int*)mask)[idx];
    pred[j] = (v != 0);
    c += pred[j];
  }
  cnt[t] = c;
  __syncthreads();
  for (int off = 1; off < 1024; off <<= 1) {
    const int v = (t >= off) ? cnt[t - off] : 0;
    __syncthreads();
    cnt[t] += v;
    __syncthreads();
  }
  int p = cnt[t] - c;               // exclusive prefix
  if (t == 1023) g_meff = cnt[1023];
#pragma unroll
  for (int j = 0; j < 6; ++j) {
    const int m = t * 6 + j;
    if (pred[j]) { g_rowmap[p] = m; g_slot[m] = p; ++p; }
    else         { g_slot[m] = -1; }
  }
}

// ------- fused prepass: per-row convert-or-zerofill (blocks 0..6143) + W1 transpose -------
__global__ void prepass_kernel(const float* __restrict__ x, ushort* __restrict__ A1,
                               const float* __restrict__ W1, ushort* __restrict__ W1T,
                               float* __restrict__ out) {
  __shared__ float tile[64][65];
  const int bid = blockIdx.x;
  const int t   = threadIdx.x;
  if (bid < M_ROWS) {
    const int slot = g_slot[bid];
    if (slot >= 0) {
      const int bb = (bid >= ROWS_PB) ? 1 : 0;
      const int s  = P_TOK + (bid - bb * ROWS_PB);
      const float* src = x + ((size_t)bb * S_TOK + s) * TEXT_H_;
      ushort* dst = A1 + (size_t)slot * TEXT_H_;
#pragma unroll
      for (int c = 0; c < 2; ++c) {
        const int base = t * 16 + c * 8;
        fl4_t f0 = *(const fl4_t*)(src + base);
        fl4_t f1 = *(const fl4_t*)(src + base + 4);
        u16x8_t o;
        o[0] = f2bf(f0[0]); o[1] = f2bf(f0[1]); o[2] = f2bf(f0[2]); o[3] = f2bf(f0[3]);
        o[4] = f2bf(f1[0]); o[5] = f2bf(f1[1]); o[6] = f2bf(f1[2]); o[7] = f2bf(f1[3]);
        *(u16x8_t*)(dst + base) = o;
      }
    } else {
      float* dst = out + (size_t)bid * NK + t * 16;
      const fl4_t z = {0.0f, 0.0f, 0.0f, 0.0f};
#pragma unroll
      for (int c = 0; c < 4; ++c) *(fl4_t*)(dst + c * 4) = z;
    }
  } else {
    const int tb = bid - M_ROWS;            // 0..4095
    const int kb = (tb & 63) * 64;
    const int nb = (tb >> 6) * 64;
    const int lr = t >> 4;
    const int lc = (t & 15) * 4;
#pragma unroll
    for (int it = 0; it < 4; ++it) {
      const int row = lr + it * 16;
      fl4_t v = *(const fl4_t*)(W1 + (size_t)(kb + row) * NK + nb + lc);
      tile[row][lc + 0] = v[0]; tile[row][lc + 1] = v[1];
      tile[row][lc + 2] = v[2]; tile[row][lc + 3] = v[3];
    }
    __syncthreads();
#pragma unroll
    for (int it = 0; it < 4; ++it) {
      const int n = lr + it * 16;
      u16x4_t o;
      o[0] = f2bf(tile[lc + 0][n]); o[1] = f2bf(tile[lc + 1][n]);
      o[2] = f2bf(tile[lc + 2][n]); o[3] = f2bf(tile[lc + 3][n]);
      *(u16x4_t*)(W1T + (size_t)(nb + n) * NK + kb + lc) = o;
    }
  }
}

// ===================== staging (r8-r14 proven chunk map + protocol) =====================
// chunk(blk,kk) = 1KB: rows blk*16..+15, k kk*32..+31; lane l <-> row blk*16+(l&15),
// k +(l>>4)*8. A: chunks 0..31, B: 32..63. Groups of 16 chunks (2 loads/thread):
//  J0: A {0-7,16-23} (afL)  J1: B rel {0-3,8-11,16-19,24-27} (bfL, all wc)
//  J2: B rel {4-7,12-15,20-23,28-31} (bfH, all wc)  J3: A {8-15,24-31} (afH)
template <int J>
__device__ __forceinline__ void stage_g0(const ushort* __restrict__ A,
                                         const ushort* __restrict__ Bt,
                                         int row0, int col0, char* lds,
                                         int tau, int w, int l) {
  char* slot = lds + (tau & 1) * SLOT0_BYTES;
  const int kt = tau * BK;
#pragma unroll
  for (int q = 0; q < 2; ++q) {
    const int cg = q * 8 + w;
    if (J == 0 || J == 3) {
      const int CH = (J == 0 ? 0 : 8) + cg + (cg & 8);
      const ushort* src = A + (size_t)(row0 + (CH >> 1) * 16 + (l & 15)) * NK
                            + kt + (CH & 1) * 32 + (l >> 4) * 8;
      gload_lds16(src, slot + CH * 1024 + l * 16);
    } else {
      const int r = (cg >> 2) * 8 + (cg & 3) + (J == 2 ? 4 : 0);
      const ushort* src = Bt + (size_t)(col0 + (r >> 1) * 16 + (l & 15)) * NK
                             + kt + (r & 1) * 32 + (l >> 4) * 8;
      gload_lds16(src, slot + (32 + r) * 1024 + l * 16);
    }
  }
}

// ---------------- compacted GEMM (r14 engine) + embedded dual-panel W2-transpose ----------
// MODE 0: Hout[r_c][c] = bf16(gelu(acc+bias)); blocks >= NWGC transpose W2 -> Wdst
//         (32 blocks x 2 panels, all 512 threads active — r18/r19-verified worker).
// MODE 1: Yout[g_rowmap[r_c]*4096+c] = f32(acc+bias) for r_c < g_meff (scatter).
template <int MODE>
__launch_bounds__(512, 2)
__global__ void gemm_c_kernel(const ushort* __restrict__ A, const ushort* __restrict__ Bt,
                              const float* __restrict__ bias,
                              const float* __restrict__ Wsrc, ushort* __restrict__ Wdst,
                              ushort* __restrict__ Hout, float* __restrict__ Yout) {
  extern __shared__ char lds[];
  const int tid = threadIdx.x;

  const int orig = blockIdx.x;
  if (MODE == 0 && orig >= NWGC) {
    // ---- W2 transpose worker: 32 blocks x 2 panels (512 thr = 2x256), 64 k-tiles each ----
    const int tw   = orig - NWGC;           // 0..31
    const int half = tid >> 8;              // 0/1 -> panel tw / tw+32
    const int ht   = tid & 255;
    float (*tile)[65] = (float(*)[65])(lds + half * 20480);
    const int nb = (tw + half * 32) * 64;
    const int lr = ht >> 4;
    const int lc = (ht & 15) * 4;
    for (int i = 0; i < 64; ++i) {
      const int kb = i * 64;
#pragma unroll
      for (int it = 0; it < 4; ++it) {
        const int row = lr + it * 16;
        fl4_t v = *(const fl4_t*)(Wsrc + (size_t)(kb + row) * NK + nb + lc);
        tile[row][lc + 0] = v[0]; tile[row][lc + 1] = v[1];
        tile[row][lc + 2] = v[2]; tile[row][lc + 3] = v[3];
      }
      __syncthreads();
#pragma unroll
      for (int it = 0; it < 4; ++it) {
        const int n = lr + it * 16;
        u16x4_t o;
        o[0] = f2bf(tile[lc + 0][n]); o[1] = f2bf(tile[lc + 1][n]);
        o[2] = f2bf(tile[lc + 2][n]); o[3] = f2bf(tile[lc + 3][n]);
        *(u16x4_t*)(Wdst + (size_t)(nb + n) * NK + kb + lc) = o;
      }
      __syncthreads();
    }
    return;
  }

  const int l   = tid & 63;
  const int w   = tid >> 6;
  const int wr  = w >> 2;         // 0..1: rows wr*128
  const int wc  = w & 3;          // 0..3: cols wc*64

  const int meff = g_meff;
  const int mt   = (meff + BM0 - 1) / BM0;   // active M-tiles
  const int nact = mt * 16;                  // active blocks; mt*16 % 8 == 0

  if (orig >= nact) return;                  // inactive blocks retire immediately
  const int bid  = (orig & 7) * (nact >> 3) + (orig >> 3);  // meff-aware XCD swizzle (r11)
  const int row0 = (bid >> 4) * BM0;
  const int col0 = (bid & 15) * BN;

  f32x4_t acc[8][4] = {};

  stage_g0<0>(A, Bt, row0, col0, lds, 0, w, l);
  stage_g0<1>(A, Bt, row0, col0, lds, 0, w, l);
  stage_g0<2>(A, Bt, row0, col0, lds, 0, w, l);
  stage_g0<3>(A, Bt, row0, col0, lds, 0, w, l);
  stage_g0<0>(A, Bt, row0, col0, lds, 1, w, l);
  stage_g0<1>(A, Bt, row0, col0, lds, 1, w, l);
  stage_g0<2>(A, Bt, row0, col0, lds, 1, w, l);
  WAIT_VM(4);                      // tile0 + J0(1) landed
  BARRIER();                       // publication barrier

  // prologue reads: afL/bfL of tile 0 (drained at P1(0)'s lgkm(4))
  bf16x8_t afL[4][2], bfL[2][2], afH[4][2], bfH[2][2];
#pragma unroll
  for (int mi = 0; mi < 4; ++mi)
#pragma unroll
    for (int kk = 0; kk < 2; ++kk)
      afL[mi][kk] = *(const bf16x8_t*)(lds + (2 * (wr * 8 + mi) + kk) * 1024 + l * 16);
#pragma unroll
  for (int ni = 0; ni < 2; ++ni)
#pragma unroll
    for (int kk = 0; kk < 2; ++kk)
      bfL[ni][kk] = *(const bf16x8_t*)(lds + (32 + 2 * (wc * 4 + ni) + kk) * 1024 + l * 16);

  for (int t = 0; t < NT; ++t) {
    char* s  = lds + (t & 1) * SLOT0_BYTES;
    char* sn = lds + ((t + 1) & 1) * SLOT0_BYTES;

    // ---- P1: issue bfH(4); stage J3(t+1); lgkm(4); MFMA LL ----
#pragma unroll
    for (int ni = 0; ni < 2; ++ni)
#pragma unroll
      for (int kk = 0; kk < 2; ++kk)
        bfH[ni][kk] = *(const bf16x8_t*)(s + (32 + 2 * (wc * 4 + 2 + ni) + kk) * 1024 + l * 16);
    if (t + 1 < NT) stage_g0<3>(A, Bt, row0, col0, lds, t + 1, w, l);
    WAIT_LGKM(4);
    __builtin_amdgcn_s_setprio(1);
#pragma unroll
    for (int mi = 0; mi < 4; ++mi)
#pragma unroll
      for (int ni = 0; ni < 2; ++ni)
#pragma unroll
        for (int kk = 0; kk < 2; ++kk)
          acc[mi][ni] = __builtin_amdgcn_mfma_f32_16x16x32_bf16(afL[mi][kk], bfL[ni][kk],
                                                                acc[mi][ni], 0, 0, 0);
    __builtin_amdgcn_s_setprio(0);
    BARRIER();   // end-P1

    // ---- P2: issue afH(8); stage J0(t+2); lgkm(8); MFMA LH (afL dies) ----
#pragma unroll
    for (int mi = 0; mi < 4; ++mi)
#pragma unroll
      for (int kk = 0; kk < 2; ++kk)
        afH[mi][kk] = *(const bf16x8_t*)(s + (2 * (wr * 8 + 4 + mi) + kk) * 1024 + l * 16);
    if (t + 2 < NT) stage_g0<0>(A, Bt, row0, col0, lds, t + 2, w, l);
    WAIT_LGKM(8);
    __builtin_amdgcn_s_setprio(1);
#pragma unroll
    for (int mi = 0; mi < 4; ++mi)
#pragma unroll
      for (int ni = 0; ni < 2; ++ni)
#pragma unroll
        for (int kk = 0; kk < 2; ++kk)
          acc[mi][2 + ni] = __builtin_amdgcn_mfma_f32_16x16x32_bf16(afL[mi][kk], bfH[ni][kk],
                                                                    acc[mi][2 + ni], 0, 0, 0);
    __builtin_amdgcn_s_setprio(0);
    BARRIER();   // end-P2

    // ---- P3: refill afL <- t+1 J0 (8); stage J1(t+2); lgkm(8); MFMA HL (bfL dies) ----
    if (t + 1 < NT) {
#pragma unroll
      for (int mi = 0; mi < 4; ++mi)
#pragma unroll
        for (int kk = 0; kk < 2; ++kk)
          afL[mi][kk] = *(const bf16x8_t*)(sn + (2 * (wr * 8 + mi) + kk) * 1024 + l * 16);
    }
    if (t + 2 < NT) stage_g0<1>(A, Bt, row0, col0, lds, t + 2, w, l);
    if (t + 1 < NT) { WAIT_LGKM(8); } else { WAIT_LGKM(0); }
    __builtin_amdgcn_s_setprio(1);
#pragma unroll
    for (int mi = 0; mi < 4; ++mi)
#pragma unroll
      for (int ni = 0; ni < 2; ++ni)
#pragma unroll
        for (int kk = 0; kk < 2; ++kk)
          acc[4 + mi][ni] = __builtin_amdgcn_mfma_f32_16x16x32_bf16(afH[mi][kk], bfL[ni][kk],
                                                                    acc[4 + mi][ni], 0, 0, 0);
    __builtin_amdgcn_s_setprio(0);
    BARRIER();   // end-P3

    // ---- P4: stage J2(t+2); VM(4); publication barrier; refill bfL <- t+1 J1; MFMA HH ----
    if (t + 2 < NT) stage_g0<2>(A, Bt, row0, col0, lds, t + 2, w, l);
    if (t >= NT - 2) { WAIT_VM(0); } else { WAIT_VM(4); }
    BARRIER();   // cross-wave DMA publication
    if (t + 1 < NT) {
#pragma unroll
      for (int ni = 0; ni < 2; ++ni)
#pragma unroll
        for (int kk = 0; kk < 2; ++kk)
          bfL[ni][kk] = *(const bf16x8_t*)(sn + (32 + 2 * (wc * 4 + ni) + kk) * 1024 + l * 16);
    }
    __builtin_amdgcn_s_setprio(1);
#pragma unroll
    for (int mi = 0; mi < 4; ++mi)
#pragma unroll
      for (int ni = 0; ni < 2; ++ni)
#pragma unroll
        for (int kk = 0; kk < 2; ++kk)
          acc[4 + mi][2 + ni] = __builtin_amdgcn_mfma_f32_16x16x32_bf16(afH[mi][kk], bfH[ni][kk],
                                                                        acc[4 + mi][2 + ni], 0, 0, 0);
    __builtin_amdgcn_s_setprio(0);
    BARRIER();   // end-P4
  }

  // epilogue: D col = lane&15, row = (lane>>4)*4 + j  (r3/r5/r9/r11-verified)
#pragma unroll
  for (int mi = 0; mi < 8; ++mi) {
#pragma unroll
    for (int j = 0; j < 4; ++j) {
      const int r = row0 + wr * 128 + mi * 16 + (l >> 4) * 4 + j;
      if (MODE == 0) {
#pragma unroll
        for (int ni = 0; ni < 4; ++ni) {
          const int c = col0 + wc * 64 + ni * 16 + (l & 15);
          float v = acc[mi][ni][j] + bias[c];
          v = 0.5f * v * (1.0f + erff(v * 0.70710678118654752f));
          Hout[(size_t)r * NK + c] = f2bf(v);
        }
      } else {
        if (r < meff) {                       // guard: rowmap beyond meff is undefined
          const int orig_row = g_rowmap[r];
          float* dst = Yout + (size_t)orig_row * NK;
#pragma unroll
          for (int ni = 0; ni < 4; ++ni) {
            const int c = col0 + wc * 64 + ni * 16 + (l & 15);
            dst[c] = acc[mi][ni][j] + bias[c];
          }
        }
      }
    }
  }
}

extern "C" void kernel_launch(void* const* d_in, const int* in_sizes, int n_in,
                              void* d_out, int out_size, void* d_ws, size_t ws_size,
                              hipStream_t stream) {
  const float* x     = (const float*)d_in[0];
  const void*  tmask = (const void*)d_in[1];
  // d_in[2] = prefix_mask (shape known: prefix_len = 4096 rows dropped)
  const float* W1    = (const float*)d_in[3];
  const float* b1    = (const float*)d_in[4];
  const float* W2    = (const float*)d_in[5];
  const float* b2    = (const float*)d_in[6];
  float* out = (float*)d_out;   // reference output dtype is float32

  const size_t offA1  = 0;
  const size_t offB1T = offA1  + (size_t)M_ROWS * NK * 2;   // 48 MiB
  const size_t offB2T = offB1T + (size_t)NK * NK * 2;       // +32 MiB
  const size_t offH   = offB2T + (size_t)NK * NK * 2;       // +32 MiB
  const size_t need   = offH   + (size_t)M_ROWS * NK * 2;   // +48 MiB = 160 MiB
  if (ws_size < need) return;

  char* ws = (char*)d_ws;
  ushort* A1  = (ushort*)(ws + offA1);
  ushort* B1T = (ushort*)(ws + offB1T);
  ushort* B2T = (ushort*)(ws + offB2T);
  ushort* H   = (ushort*)(ws + offH);

  // 1. scan mask -> meff/rowmap/slot
  scan_mask_kernel<<<dim3(1), dim3(1024), 0, stream>>>(tmask);
  // 2. fused prepass: convert mask=1 rows -> A1, zero-fill mask=0 out rows, transpose W1
  prepass_kernel<<<dim3(M_ROWS + 4096), dim3(256), 0, stream>>>(x, A1, W1, B1T, out);
  // 3. GEMM1 (+32 embedded dual-panel W2-transpose blocks; residency <= 256)
  gemm_c_kernel<0><<<dim3(NWGC + TW2_BLKS), dim3(512), LDS0_TOTAL, stream>>>(
      A1, B1T, b1, W2, B2T, H, nullptr);
  // 4. GEMM2 (scatter to mask=1 rows; mask=0 rows already zeroed by prepass)
  gemm_c_kernel<1><<<dim3(NWGC), dim3(512), LDS0_TOTAL, stream>>>(
      H, B2T, b2, nullptr, nullptr, nullptr, out);
}